// Round 9
// baseline (486.512 us; speedup 1.0000x reference)
//
#include <hip/hip_runtime.h>
#include <hip/hip_bf16.h>
#include <stdint.h>

// ---------------------------------------------------------------------------
// BondPoolingLayer: out[e] = MLP(cat(h[src],h[dst])) + MLP(cat(h[dst],h[src]))
// MLP: 256 ->(W1,b1,relu) 128 ->(W2,b2,relu) 128 ->(W3,b3) 2
//
// P[n,0:128] = h[n] @ W1_top ; P[n,128:256] = h[n] @ W1_bot + b1   (bf16)
//   fwd layer1 preact = P[s,0:128] + P[d,128:256]
//   rev layer1 preact = P[d,0:128] + P[s,128:256]
//
// R9: R6/R8's persistent-contiguous pipeline regressed because of VGPR
// SPILLS (VGPR_Count=128 + ~110-170MB of scratch traffic on both FETCH and
// WRITE). This round re-runs the pipeline with the live set held under the
// 128-VGPR / 4-waves-per-SIMD cap:
//  - node_proj: persistent contiguous tiles, W1 staged from pre-transposed
//    bf16 W1t (coalesced, short-lived temps), steady-state live regs
//    acc(64)+bfrag(16)+hreg-prefetch(32) ~= 112, __launch_bounds__(512,4).
//  - edge_mlp: R7-proven burst version, verbatim (VGPR ~60, no spills).
// ---------------------------------------------------------------------------

typedef __attribute__((ext_vector_type(8))) short bf16x8;
typedef __attribute__((ext_vector_type(4))) float f32x4;

__device__ __forceinline__ float bf2f(unsigned u16) {
    union { unsigned u; float f; } v; v.u = u16 << 16;
    return v.f;
}
__device__ __forceinline__ unsigned short f2bf(float f) {
    union { float f; unsigned u; } v; v.f = f;
    unsigned u = v.u;
    unsigned r = u + 0x7FFFu + ((u >> 16) & 1u);   // RNE
    return (unsigned short)(r >> 16);
}

// LDS swizzle for weight tiles [rows][128 bf16], chunk = 8 bf16 (16B).
__device__ __forceinline__ int swz(int f, int c) {
    return f * 128 + ((c ^ (f & 7)) << 3);
}

// elementwise relu(a+b) over 8 bf16 pairs (fp32 math), repacked to bf16x8
__device__ __forceinline__ bf16x8 addrelu8(uint4 a, uint4 b) {
    union { uint4 v; unsigned u[4]; } A, B;
    A.v = a; B.v = b;
    union { bf16x8 v; __hip_bfloat162 h[4]; } R;
#pragma unroll
    for (int i = 0; i < 4; ++i) {
        float a0 = bf2f(A.u[i] & 0xFFFFu), a1 = bf2f(A.u[i] >> 16);
        float b0 = bf2f(B.u[i] & 0xFFFFu), b1 = bf2f(B.u[i] >> 16);
        R.h[i] = __float22bfloat162_rn(float2{fmaxf(a0 + b0, 0.f),
                                              fmaxf(a1 + b1, 0.f)});
    }
    return R.v;
}

// pack 8 fp32 (RNE) -> uint4 of 8 bf16
__device__ __forceinline__ uint4 pack8(const float* v) {
    union { uint4 u; __hip_bfloat162 h[4]; } R;
#pragma unroll
    for (int i = 0; i < 4; ++i)
        R.h[i] = __float22bfloat162_rn(float2{v[2 * i], v[2 * i + 1]});
    return R.u;
}

#define MFMA(a, b, c) __builtin_amdgcn_mfma_f32_16x16x32_bf16((a), (b), (c), 0, 0, 0)

// ---------------------------------------------------------------------------
// Kernel 0: W1 transpose to bf16.
// W1t[j][k] (j in [0,256), k in [0,128)) = W1[k][j] (j<128) | W1[k+128][j-128]
// ---------------------------------------------------------------------------
__global__ void prep_weights(const float* __restrict__ W1,
                             unsigned short* __restrict__ W1t) {
    int idx = blockIdx.x * 256 + threadIdx.x;
    if (idx < 256 * 128) {
        int j = idx >> 7, k = idx & 127;
        float v = (j < 128) ? W1[k * 128 + j] : W1[(k + 128) * 128 + (j - 128)];
        W1t[idx] = f2bf(v);
    }
}

// ---------------------------------------------------------------------------
// Kernel A: node projection, persistent-contiguous, spill-free.
// Block = 512 thr; tile = 128 nodes; wave = 16 nodes x 256 features.
// W1t staged coalesced into LDS once per block (amortized over `per` tiles).
// ---------------------------------------------------------------------------
__global__ __launch_bounds__(512, 4) void node_proj(
    const float* __restrict__ h, const unsigned short* __restrict__ W1t,
    const float* __restrict__ b1, unsigned short* __restrict__ P,
    int nodes, int ntiles, int per) {
    __shared__ unsigned short W1s[256 * 128];   // 64 KB

    int t = threadIdx.x;
    int lane = t & 63;
    int wv = t >> 6;
    int ml = lane & 15, quad = lane >> 4;

    // stage W1s coalesced: thread t -> row t>>1, 8 chunks (swizzled)
    {
        int r = t >> 1, half = t & 1;
        const uint4* src = (const uint4*)(W1t + (size_t)r * 128 + half * 64);
#pragma unroll
        for (int i = 0; i < 8; ++i)
            *(uint4*)(W1s + swz(r, half * 8 + i)) = src[i];
    }

    int t0 = blockIdx.x * per;
    int t1 = t0 + per; if (t1 > ntiles) t1 = ntiles;

    // prefetch first tile's h rows
    float4 hreg[8];
    if (t0 < t1) {
        int nd = t0 * 128 + wv * 16 + ml;
        if (nd >= nodes) nd = nodes - 1;
        const float4* hp = (const float4*)(h + (size_t)nd * 128);
#pragma unroll
        for (int kk = 0; kk < 4; ++kk) {
            hreg[2 * kk]     = hp[kk * 8 + quad * 2];
            hreg[2 * kk + 1] = hp[kk * 8 + quad * 2 + 1];
        }
    }

    __syncthreads();   // W1s ready

    for (int tile = t0; tile < t1; ++tile) {
        // consume hreg -> bf16 B fragments (hreg dead after this)
        bf16x8 bfrag[4];
#pragma unroll
        for (int kk = 0; kk < 4; ++kk) {
            union { bf16x8 v; __hip_bfloat162 hh[4]; } R;
            float4 x = hreg[2 * kk], y = hreg[2 * kk + 1];
            R.hh[0] = __float22bfloat162_rn(float2{x.x, x.y});
            R.hh[1] = __float22bfloat162_rn(float2{x.z, x.w});
            R.hh[2] = __float22bfloat162_rn(float2{y.x, y.y});
            R.hh[3] = __float22bfloat162_rn(float2{y.z, y.w});
            bfrag[kk] = R.v;
        }

        int node = tile * 128 + wv * 16 + ml;

        // issue next tile's loads into hreg (overlaps MFMA + stores below)
        if (tile + 1 < t1) {
            int nd = (tile + 1) * 128 + wv * 16 + ml;
            if (nd >= nodes) nd = nodes - 1;
            const float4* hp = (const float4*)(h + (size_t)nd * 128);
#pragma unroll
            for (int kk = 0; kk < 4; ++kk) {
                hreg[2 * kk]     = hp[kk * 8 + quad * 2];
                hreg[2 * kk + 1] = hp[kk * 8 + quad * 2 + 1];
            }
        }

        f32x4 acc[16] = {};
#pragma unroll
        for (int kk = 0; kk < 4; ++kk) {
#pragma unroll
            for (int ct = 0; ct < 16; ++ct) {
                bf16x8 afrag = *(const bf16x8*)(W1s + swz(ct * 16 + ml, kk * 4 + quad));
                acc[ct] = MFMA(afrag, bfrag[kk], acc[ct]);
            }
        }

        // epilogue: lane ml owns node; features = ct*16 + quad*4 + reg
        if (node < nodes) {
            unsigned short* prow = P + (size_t)node * 256;
#pragma unroll
            for (int ct = 0; ct < 16; ++ct) {
                int fbase = ct * 16 + quad * 4;
                float v0 = acc[ct][0], v1 = acc[ct][1];
                float v2 = acc[ct][2], v3 = acc[ct][3];
                if (fbase >= 128) {
                    float4 bv = *(const float4*)(b1 + (fbase - 128));
                    v0 += bv.x; v1 += bv.y; v2 += bv.z; v3 += bv.w;
                }
                union { uint2 u; __hip_bfloat162 h2[2]; } o;
                o.h2[0] = __float22bfloat162_rn(float2{v0, v1});
                o.h2[1] = __float22bfloat162_rn(float2{v2, v3});
                *(uint2*)(prow + fbase) = o.u;
            }
        }
    }
}

// ---------------------------------------------------------------------------
// Kernel B: per-edge MLP (R7-proven burst version, verbatim).
// Block = 512 thr = 8 waves = 128 edges. Wave = 16 edges x {fwd,rev}.
// ---------------------------------------------------------------------------
__global__ __launch_bounds__(512, 2) void edge_mlp(
    const unsigned short* __restrict__ P, const int* __restrict__ src,
    const int* __restrict__ dst, const float* __restrict__ W2,
    const float* __restrict__ b2, const float* __restrict__ W3,
    const float* __restrict__ b3, float* __restrict__ out, int E) {
    __shared__ unsigned short W2s[128 * 128];

    int t = threadIdx.x;
    int lane = t & 63;
    int wv = t >> 6;
    int ml = lane & 15, quad = lane >> 4;

    // ---- stage W2^T into LDS directly from fp32 W2: row f, chunks of 8 k
    {
        int f = t >> 2, q4 = t & 3;
        const float* col = W2 + f;
#pragma unroll
        for (int ci = 0; ci < 4; ++ci) {
            int c = q4 * 4 + ci;
            float v[8];
#pragma unroll
            for (int l = 0; l < 8; ++l)
                v[l] = col[(c * 8 + l) * 128];
            *(uint4*)(W2s + swz(f, c)) = pack8(v);
        }
    }

    // ---- prefetch all P gathers for this lane's edge
    int e = blockIdx.x * 128 + wv * 16 + ml;
    int ec = (e < E) ? e : (E - 1);
    int si = src[ec], di = dst[ec];
    const unsigned short* Ps = P + (size_t)si * 256;
    const unsigned short* Pd = P + (size_t)di * 256;

    uint4 g[4][4];   // [kk][s_lo, s_hi, d_lo, d_hi]
#pragma unroll
    for (int kk = 0; kk < 4; ++kk) {
        int ko = kk * 32 + quad * 8;
        g[kk][0] = *(const uint4*)(Ps + ko);
        g[kk][1] = *(const uint4*)(Ps + 128 + ko);
        g[kk][2] = *(const uint4*)(Pd + ko);
        g[kk][3] = *(const uint4*)(Pd + 128 + ko);
    }

    __syncthreads();   // W2s ready

    f32x4 acc[2][8] = {};
#pragma unroll
    for (int kk = 0; kk < 4; ++kk) {
        bf16x8 afw = addrelu8(g[kk][0], g[kk][3]);   // fwd: relu(P[s,k]+P[d,128+k])
        bf16x8 arv = addrelu8(g[kk][2], g[kk][1]);   // rev: relu(P[d,k]+P[s,128+k])
#pragma unroll
        for (int ct = 0; ct < 8; ++ct) {
            bf16x8 bfrag = *(const bf16x8*)(W2s + swz(ct * 16 + ml, kk * 4 + quad));
            acc[0][ct] = MFMA(afw, bfrag, acc[0][ct]);
            acc[1][ct] = MFMA(arv, bfrag, acc[1][ct]);
        }
    }

    // ---- epilogue: +b2, relu, dot W3 columns, butterfly over 16 feature lanes
    float w30[8], w31[8], b2v[8];
#pragma unroll
    for (int ct = 0; ct < 8; ++ct) {
        int c = ct * 16 + ml;
        w30[ct] = W3[c * 2 + 0];
        w31[ct] = W3[c * 2 + 1];
        b2v[ct] = b2[c];
    }
    float p0[2][4], p1[2][4];
#pragma unroll
    for (int rt = 0; rt < 2; ++rt)
#pragma unroll
        for (int reg = 0; reg < 4; ++reg) { p0[rt][reg] = 0.f; p1[rt][reg] = 0.f; }
#pragma unroll
    for (int rt = 0; rt < 2; ++rt)
#pragma unroll
        for (int ct = 0; ct < 8; ++ct)
#pragma unroll
            for (int reg = 0; reg < 4; ++reg) {
                float h2 = fmaxf(acc[rt][ct][reg] + b2v[ct], 0.f);
                p0[rt][reg] += h2 * w30[ct];
                p1[rt][reg] += h2 * w31[ct];
            }
#pragma unroll
    for (int m = 1; m < 16; m <<= 1) {
#pragma unroll
        for (int rt = 0; rt < 2; ++rt)
#pragma unroll
            for (int reg = 0; reg < 4; ++reg) {
                p0[rt][reg] += __shfl_xor(p0[rt][reg], m);
                p1[rt][reg] += __shfl_xor(p1[rt][reg], m);
            }
    }

    if (ml < 2) {
        float bb = 2.f * b3[ml];
#pragma unroll
        for (int reg = 0; reg < 4; ++reg) {
            int ee = blockIdx.x * 128 + wv * 16 + quad * 4 + reg;
            if (ee < E) {
                float v = (ml == 0) ? (p0[0][reg] + p0[1][reg])
                                    : (p1[0][reg] + p1[1][reg]);
                out[(size_t)ee * 2 + ml] = v + bb;
            }
        }
    }
}

// ---------------------------------------------------------------------------
extern "C" void kernel_launch(void* const* d_in, const int* in_sizes, int n_in,
                              void* d_out, int out_size, void* d_ws, size_t ws_size,
                              hipStream_t stream) {
    (void)n_in; (void)out_size; (void)ws_size;
    const float* h  = (const float*)d_in[0];
    const int*   sr = (const int*)d_in[1];
    const int*   ds = (const int*)d_in[2];
    const float* W1 = (const float*)d_in[3];
    const float* b1 = (const float*)d_in[4];
    const float* W2 = (const float*)d_in[5];
    const float* b2 = (const float*)d_in[6];
    const float* W3 = (const float*)d_in[7];
    const float* b3 = (const float*)d_in[8];
    float* out = (float*)d_out;

    int nodes = in_sizes[0] / 128;
    int E = in_sizes[1];

    unsigned short* W1t = (unsigned short*)d_ws;   // 256*128 bf16
    unsigned short* P   = W1t + 256 * 128;         // nodes*256 bf16

    prep_weights<<<128, 256, 0, stream>>>(W1, W1t);

    int ntiles = (nodes + 127) / 128;
    int ngrid = (ntiles < 512) ? ntiles : 512;
    int nper = (ntiles + ngrid - 1) / ngrid;
    node_proj<<<ngrid, 512, 0, stream>>>(h, W1t, b1, P, nodes, ntiles, nper);

    int etiles = (E + 127) / 128;
    edge_mlp<<<etiles, 512, 0, stream>>>(P, sr, ds, W2, b2, W3, b3, out, E);
}

// Round 10
// 410.648 us; speedup vs baseline: 1.1847x; 1.1847x over previous
//
#include <hip/hip_runtime.h>
#include <hip/hip_bf16.h>
#include <hip/hip_cooperative_groups.h>
#include <stdint.h>

namespace cg = cooperative_groups;

// ---------------------------------------------------------------------------
// BondPoolingLayer: out[e] = MLP(cat(h[src],h[dst])) + MLP(cat(h[dst],h[src]))
// MLP: 256 ->(W1,b1,relu) 128 ->(W2,b2,relu) 128 ->(W3,b3) 2
//
// P[n,0:128] = h[n] @ W1_top ; P[n,128:256] = h[n] @ W1_bot + b1   (bf16)
//   fwd layer1 preact = P[s,0:128] + P[d,128:256]
//   rev layer1 preact = P[d,0:128] + P[s,128:256]
//
// R10: ONE cooperative dispatch. Phase A = R5-proven node burst (64KB W1 in
// LDS, contiguous tile chunk, no cross-tile prefetch -> no spills). Re-stage
// W2 into the same LDS while waiting, grid.sync(), Phase B = R7-proven edge
// burst. Removes 2 launch gaps + prep kernel; P stays L2/L3-warm into B.
// Numerics bit-identical to R5/R7 (absmax 0.03125).
// ---------------------------------------------------------------------------

typedef __attribute__((ext_vector_type(8))) short bf16x8;
typedef __attribute__((ext_vector_type(4))) float f32x4;

__device__ __forceinline__ float bf2f(unsigned u16) {
    union { unsigned u; float f; } v; v.u = u16 << 16;
    return v.f;
}

// LDS swizzle for weight tiles [rows][128 bf16], chunk = 8 bf16 (16B).
__device__ __forceinline__ int swz(int f, int c) {
    return f * 128 + ((c ^ (f & 7)) << 3);
}

// elementwise relu(a+b) over 8 bf16 pairs (fp32 math), repacked to bf16x8
__device__ __forceinline__ bf16x8 addrelu8(uint4 a, uint4 b) {
    union { uint4 v; unsigned u[4]; } A, B;
    A.v = a; B.v = b;
    union { bf16x8 v; __hip_bfloat162 h[4]; } R;
#pragma unroll
    for (int i = 0; i < 4; ++i) {
        float a0 = bf2f(A.u[i] & 0xFFFFu), a1 = bf2f(A.u[i] >> 16);
        float b0 = bf2f(B.u[i] & 0xFFFFu), b1 = bf2f(B.u[i] >> 16);
        R.h[i] = __float22bfloat162_rn(float2{fmaxf(a0 + b0, 0.f),
                                              fmaxf(a1 + b1, 0.f)});
    }
    return R.v;
}

// pack 8 fp32 (RNE) -> uint4 of 8 bf16
__device__ __forceinline__ uint4 pack8(const float* v) {
    union { uint4 u; __hip_bfloat162 h[4]; } R;
#pragma unroll
    for (int i = 0; i < 4; ++i)
        R.h[i] = __float22bfloat162_rn(float2{v[2 * i], v[2 * i + 1]});
    return R.u;
}

#define MFMA(a, b, c) __builtin_amdgcn_mfma_f32_16x16x32_bf16((a), (b), (c), 0, 0, 0)

// ---------------------------------------------------------------------------
// Fused cooperative kernel. Block = 512 thr = 8 waves.
// ---------------------------------------------------------------------------
__global__ __launch_bounds__(512, 2) void bond_fused(
    const float* __restrict__ h, const int* __restrict__ src,
    const int* __restrict__ dst, const float* __restrict__ W1,
    const float* __restrict__ b1, const float* __restrict__ W2,
    const float* __restrict__ b2, const float* __restrict__ W3,
    const float* __restrict__ b3, unsigned short* __restrict__ P,
    float* __restrict__ out, int nodes, int E, int ntiles, int etiles,
    int nper, int eper) {
    __shared__ unsigned short Ws[256 * 128];   // 64 KB; phase B uses first 32 KB

    int t = threadIdx.x;
    int lane = t & 63;
    int wv = t >> 6;
    int ml = lane & 15, quad = lane >> 4;

    // ---- stage W1cat^T into LDS from fp32 (R7 pattern): row j, 16 chunks
    {
        int j = t >> 1, halfc = t & 1;
        const float* col = (j < 128) ? (W1 + j) : (W1 + 128 * 128 + (j - 128));
#pragma unroll
        for (int ci = 0; ci < 8; ++ci) {
            int c = halfc * 8 + ci;            // chunk: k in [c*8, c*8+8)
            float v[8];
#pragma unroll
            for (int l = 0; l < 8; ++l)
                v[l] = col[(c * 8 + l) * 128];
            *(uint4*)(Ws + swz(j, c)) = pack8(v);
        }
    }
    __syncthreads();   // W1 ready

    // ---- phase A: node projection, contiguous tile chunk, burst per tile
    {
        int t0 = blockIdx.x * nper;
        int t1 = t0 + nper; if (t1 > ntiles) t1 = ntiles;
        for (int tile = t0; tile < t1; ++tile) {
            int node = tile * 128 + wv * 16 + ml;
            int nodeL = (node < nodes) ? node : (nodes - 1);
            const float4* hp = (const float4*)(h + (size_t)nodeL * 128);
            bf16x8 bfrag[4];
#pragma unroll
            for (int kk = 0; kk < 4; ++kk) {
                float4 x = hp[kk * 8 + quad * 2];
                float4 y = hp[kk * 8 + quad * 2 + 1];
                union { bf16x8 v; __hip_bfloat162 hh[4]; } R;
                R.hh[0] = __float22bfloat162_rn(float2{x.x, x.y});
                R.hh[1] = __float22bfloat162_rn(float2{x.z, x.w});
                R.hh[2] = __float22bfloat162_rn(float2{y.x, y.y});
                R.hh[3] = __float22bfloat162_rn(float2{y.z, y.w});
                bfrag[kk] = R.v;
            }

            f32x4 acc[16] = {};
#pragma unroll
            for (int kk = 0; kk < 4; ++kk) {
#pragma unroll
                for (int ct = 0; ct < 16; ++ct) {
                    bf16x8 afrag = *(const bf16x8*)(Ws + swz(ct * 16 + ml, kk * 4 + quad));
                    acc[ct] = MFMA(afrag, bfrag[kk], acc[ct]);
                }
            }

            if (node < nodes) {
                unsigned short* prow = P + (size_t)node * 256;
#pragma unroll
                for (int ct = 0; ct < 16; ++ct) {
                    int fbase = ct * 16 + quad * 4;
                    float v0 = acc[ct][0], v1 = acc[ct][1];
                    float v2 = acc[ct][2], v3 = acc[ct][3];
                    if (fbase >= 128) {
                        float4 bv = *(const float4*)(b1 + (fbase - 128));
                        v0 += bv.x; v1 += bv.y; v2 += bv.z; v3 += bv.w;
                    }
                    union { uint2 u; __hip_bfloat162 h2[2]; } o;
                    o.h2[0] = __float22bfloat162_rn(float2{v0, v1});
                    o.h2[1] = __float22bfloat162_rn(float2{v2, v3});
                    *(uint2*)(prow + fbase) = o.u;
                }
            }
        }
    }

    __syncthreads();   // all waves done reading W1 region

    // ---- stage W2^T into first 32 KB (overlaps the wait for other blocks)
    {
        int f = t >> 2, q4 = t & 3;
        const float* col = W2 + f;
#pragma unroll
        for (int ci = 0; ci < 4; ++ci) {
            int c = q4 * 4 + ci;
            float v[8];
#pragma unroll
            for (int l = 0; l < 8; ++l)
                v[l] = col[(c * 8 + l) * 128];
            *(uint4*)(Ws + swz(f, c)) = pack8(v);
        }
    }

    // loop-invariant epilogue constants (live range starts post-phase-A)
    float w30[8], w31[8], b2v[8];
#pragma unroll
    for (int ct = 0; ct < 8; ++ct) {
        int c = ct * 16 + ml;
        w30[ct] = W3[c * 2 + 0];
        w31[ct] = W3[c * 2 + 1];
        b2v[ct] = b2[c];
    }
    float bb0 = 2.f * b3[0], bb1 = 2.f * b3[1];

    cg::this_grid().sync();   // P complete device-wide; W2s staged

    // ---- phase B: per-edge MLP, contiguous tile chunk, burst per tile
    {
        int t0 = blockIdx.x * eper;
        int t1 = t0 + eper; if (t1 > etiles) t1 = etiles;
        for (int tile = t0; tile < t1; ++tile) {
            int e = tile * 128 + wv * 16 + ml;
            int ec = (e < E) ? e : (E - 1);
            int si = src[ec], di = dst[ec];
            const unsigned short* Ps = P + (size_t)si * 256;
            const unsigned short* Pd = P + (size_t)di * 256;

            f32x4 acc[2][8] = {};
#pragma unroll
            for (int kk = 0; kk < 4; ++kk) {
                int ko = kk * 32 + quad * 8;
                uint4 g0 = *(const uint4*)(Ps + ko);
                uint4 g1 = *(const uint4*)(Ps + 128 + ko);
                uint4 g2 = *(const uint4*)(Pd + ko);
                uint4 g3 = *(const uint4*)(Pd + 128 + ko);
                bf16x8 afw = addrelu8(g0, g3);   // fwd: relu(P[s,k]+P[d,128+k])
                bf16x8 arv = addrelu8(g2, g1);   // rev: relu(P[d,k]+P[s,128+k])
#pragma unroll
                for (int ct = 0; ct < 8; ++ct) {
                    bf16x8 bfrag = *(const bf16x8*)(Ws + swz(ct * 16 + ml, kk * 4 + quad));
                    acc[0][ct] = MFMA(afw, bfrag, acc[0][ct]);
                    acc[1][ct] = MFMA(arv, bfrag, acc[1][ct]);
                }
            }

            float p0[2][4], p1[2][4];
#pragma unroll
            for (int rt = 0; rt < 2; ++rt)
#pragma unroll
                for (int reg = 0; reg < 4; ++reg) { p0[rt][reg] = 0.f; p1[rt][reg] = 0.f; }
#pragma unroll
            for (int rt = 0; rt < 2; ++rt)
#pragma unroll
                for (int ct = 0; ct < 8; ++ct)
#pragma unroll
                    for (int reg = 0; reg < 4; ++reg) {
                        float h2 = fmaxf(acc[rt][ct][reg] + b2v[ct], 0.f);
                        p0[rt][reg] += h2 * w30[ct];
                        p1[rt][reg] += h2 * w31[ct];
                    }
#pragma unroll
            for (int m = 1; m < 16; m <<= 1) {
#pragma unroll
                for (int rt = 0; rt < 2; ++rt)
#pragma unroll
                    for (int reg = 0; reg < 4; ++reg) {
                        p0[rt][reg] += __shfl_xor(p0[rt][reg], m);
                        p1[rt][reg] += __shfl_xor(p1[rt][reg], m);
                    }
            }

            if (ml < 2) {
#pragma unroll
                for (int reg = 0; reg < 4; ++reg) {
                    int ee = tile * 128 + wv * 16 + quad * 4 + reg;
                    if (ee < E) {
                        float v = (ml == 0) ? (p0[0][reg] + p0[1][reg] + bb0)
                                            : (p1[0][reg] + p1[1][reg] + bb1);
                        out[(size_t)ee * 2 + ml] = v;
                    }
                }
            }
        }
    }
}

// ---------------------------------------------------------------------------
extern "C" void kernel_launch(void* const* d_in, const int* in_sizes, int n_in,
                              void* d_out, int out_size, void* d_ws, size_t ws_size,
                              hipStream_t stream) {
    (void)n_in; (void)out_size; (void)ws_size;
    const float* h  = (const float*)d_in[0];
    const int*   sr = (const int*)d_in[1];
    const int*   ds = (const int*)d_in[2];
    const float* W1 = (const float*)d_in[3];
    const float* b1 = (const float*)d_in[4];
    const float* W2 = (const float*)d_in[5];
    const float* b2 = (const float*)d_in[6];
    const float* W3 = (const float*)d_in[7];
    const float* b3 = (const float*)d_in[8];
    float* out = (float*)d_out;

    int nodes = in_sizes[0] / 128;
    int E = in_sizes[1];

    unsigned short* P = (unsigned short*)d_ws;   // nodes*256 bf16

    int ntiles = (nodes + 127) / 128;
    int etiles = (E + 127) / 128;

    // co-residency-safe cooperative grid (deterministic across calls)
    int maxb = 1;
    hipOccupancyMaxActiveBlocksPerMultiprocessor(&maxb, (const void*)bond_fused, 512, 0);
    if (maxb < 1) maxb = 1;
    long long grid = 256LL * maxb;
    if (grid > 512) grid = 512;
    int gridi = (int)grid;

    int nper = (ntiles + gridi - 1) / gridi;
    int eper = (etiles + gridi - 1) / gridi;

    void* args[] = {(void*)&h, (void*)&sr, (void*)&ds, (void*)&W1, (void*)&b1,
                    (void*)&W2, (void*)&b2, (void*)&W3, (void*)&b3, (void*)&P,
                    (void*)&out, (void*)&nodes, (void*)&E, (void*)&ntiles,
                    (void*)&etiles, (void*)&nper, (void*)&eper};
    hipLaunchCooperativeKernel((const void*)bond_fused, dim3(gridi), dim3(512),
                               args, 0, stream);
}